// Round 1
// baseline (559.858 us; speedup 1.0000x reference)
//
#include <hip/hip_runtime.h>
#include <math.h>

#define N_ENT 150000
#define N_REL 500
#define H     128
#define DEG   32
#define TOPK  10

// ---------------------------------------------------------------------------
// Kernel A: tiny precomputes.
//   blocks 0..127 : row r of M = W @ nw  and M2 = W_r @ nw
//   block  128    : v1 = W@a1, v2 = W@a2, u3 = W_r@a3
// ---------------------------------------------------------------------------
__global__ __launch_bounds__(128) void precompute_small(
    const float* __restrict__ W, const float* __restrict__ Wr,
    const float* __restrict__ nw, const float* __restrict__ a,
    float* __restrict__ M, float* __restrict__ M2,
    float* __restrict__ v1, float* __restrict__ v2, float* __restrict__ u3)
{
    int j = threadIdx.x;
    if (blockIdx.x < H) {
        int r = blockIdx.x;
        float m = 0.f, m2 = 0.f;
        for (int t = 0; t < H; ++t) {
            float x = nw[t * H + j];          // coalesced across j
            m  += W [r * H + t] * x;          // uniform
            m2 += Wr[r * H + t] * x;
        }
        M [r * H + j] = m;
        M2[r * H + j] = m2;
    } else {
        int h = j;
        float s1 = 0.f, s2 = 0.f, s3 = 0.f;
        for (int t = 0; t < H; ++t) {
            s1 += W [h * H + t] * a[t];
            s2 += W [h * H + t] * a[H + t];
            s3 += Wr[h * H + t] * a[2 * H + t];
        }
        v1[h] = s1; v2[h] = s2; u3[h] = s3;
    }
}

// ---------------------------------------------------------------------------
// Kernel B: R = rel_emb @ M2 (500x128), s_rel = rel_emb @ u3 (500)
// ---------------------------------------------------------------------------
__global__ __launch_bounds__(128) void rel_transform(
    const float* __restrict__ rel, const float* __restrict__ M2,
    const float* __restrict__ u3, float* __restrict__ R,
    float* __restrict__ srel)
{
    __shared__ float red[H];
    int r = blockIdx.x, j = threadIdx.x;
    float acc = 0.f;
    for (int h = 0; h < H; ++h)
        acc += rel[r * H + h] * M2[h * H + j];   // uniform * coalesced
    R[r * H + j] = acc;
    red[j] = rel[r * H + j] * u3[j];
    __syncthreads();
    for (int s = 64; s > 0; s >>= 1) {
        if (j < s) red[j] += red[j + s];
        __syncthreads();
    }
    if (j == 0) srel[r] = red[0];
}

// ---------------------------------------------------------------------------
// Kernel D0: s_src[i] = ent[i]·v1, s_dst[i] = ent[i]·v2.  One wave per row,
// coalesced 512B row reads, butterfly shuffle reduction. HBM-bound (~77MB).
// ---------------------------------------------------------------------------
__global__ __launch_bounds__(256) void node_scores(
    const float* __restrict__ ent, const float* __restrict__ v1,
    const float* __restrict__ v2, float* __restrict__ ssrc,
    float* __restrict__ sdst)
{
    int lane = threadIdx.x & 63;
    int w    = (blockIdx.x * blockDim.x + threadIdx.x) >> 6;
    int nw_  = (gridDim.x * blockDim.x) >> 6;
    float v1a = v1[lane], v1b = v1[lane + 64];
    float v2a = v2[lane], v2b = v2[lane + 64];
    for (int r = w; r < N_ENT; r += nw_) {
        float e0 = ent[(size_t)r * H + lane];
        float e1 = ent[(size_t)r * H + lane + 64];
        float p1 = e0 * v1a + e1 * v1b;
        float p2 = e0 * v2a + e1 * v2b;
        for (int off = 32; off > 0; off >>= 1) {
            p1 += __shfl_xor(p1, off);
            p2 += __shfl_xor(p2, off);
        }
        if (lane == 0) { ssrc[r] = p1; sdst[r] = p2; }
    }
}

// ---------------------------------------------------------------------------
// Kernel C: G = ent_emb @ M  (150000x128 @ 128x128, f32 vector ALU).
// M staged in LDS (64KB -> 2 blocks/CU). 16-row tiles, 2 col-groups of 128
// threads, 8-row register blocking amortizes LDS M reads 8x. ent rows read
// via wave-uniform (scalar) loads.
// ---------------------------------------------------------------------------
__global__ __launch_bounds__(256) void ent_transform(
    const float* __restrict__ ent, const float* __restrict__ M,
    float* __restrict__ G)
{
    __shared__ float Ml[H * H];
    for (int t = threadIdx.x; t < H * H / 4; t += 256)
        ((float4*)Ml)[t] = ((const float4*)M)[t];
    __syncthreads();

    int j = threadIdx.x & 127;
    int g = __builtin_amdgcn_readfirstlane(threadIdx.x >> 7);  // wave-uniform
    const int nTiles = N_ENT / 16;  // 9375
    for (int tile = blockIdx.x; tile < nTiles; tile += gridDim.x) {
        const float* eb = ent + ((size_t)tile * 16 + g * 8) * H;
        float acc[8] = {0.f, 0.f, 0.f, 0.f, 0.f, 0.f, 0.f, 0.f};
        for (int h = 0; h < H; h += 4) {
            float m0 = Ml[(h + 0) * H + j];
            float m1 = Ml[(h + 1) * H + j];
            float m2 = Ml[(h + 2) * H + j];
            float m3 = Ml[(h + 3) * H + j];
            #pragma unroll
            for (int r = 0; r < 8; ++r) {
                float4 e = *(const float4*)(eb + r * H + h);   // uniform load
                acc[r] += e.x * m0 + e.y * m1 + e.z * m2 + e.w * m3;
            }
        }
        float* go = G + ((size_t)tile * 16 + g * 8) * H + j;
        #pragma unroll
        for (int r = 0; r < 8; ++r) go[(size_t)r * H] = acc[r];   // coalesced
    }
}

// ---------------------------------------------------------------------------
// Kernel D: fused score-gather + top-10 (jax tie-break: max value, min index)
// + softmax + weighted G/R row gather + tanh.  One 32-lane half-wave per node.
// ---------------------------------------------------------------------------
__global__ __launch_bounds__(256) void gather_topk_out(
    const int* __restrict__ src, const int* __restrict__ rel_id,
    const float* __restrict__ ssrc, const float* __restrict__ sdst,
    const float* __restrict__ srel, const float* __restrict__ G,
    const float* __restrict__ R, float* __restrict__ out)
{
    int l   = threadIdx.x & 31;
    int hw  = (blockIdx.x * blockDim.x + threadIdx.x) >> 5;
    int nhw = (gridDim.x * blockDim.x) >> 5;
    for (int i = hw; i < N_ENT; i += nhw) {
        int sidx = src   [(size_t)i * DEG + l];
        int ridx = rel_id[(size_t)i * DEG + l];
        float x   = ssrc[sidx] + sdst[i] + srel[ridx];
        float val = x >= 0.f ? x : 0.2f * x;          // leaky_relu(0.2)

        // iterative argmax (value desc, index asc on ties) == jax.lax.top_k
        float curv = val;
        float tvv[TOPK]; int ts[TOPK], tr[TOPK];
        #pragma unroll
        for (int k = 0; k < TOPK; ++k) {
            float v = curv; int id = l;
            #pragma unroll
            for (int off = 1; off < 32; off <<= 1) {
                float v2 = __shfl_xor(v, off, 32);
                int   i2 = __shfl_xor(id, off, 32);
                if (v2 > v || (v2 == v && i2 < id)) { v = v2; id = i2; }
            }
            tvv[k] = v;
            ts[k] = __shfl(sidx, id, 32);
            tr[k] = __shfl(ridx, id, 32);
            if (l == id) curv = -INFINITY;
        }

        // softmax over the 10 kept scores (tvv[0] is the max)
        float m = tvv[0], wsum = 0.f, wk[TOPK];
        #pragma unroll
        for (int k = 0; k < TOPK; ++k) { wk[k] = __expf(tvv[k] - m); wsum += wk[k]; }
        float inv = 1.f / wsum;

        // out[i] = tanh( sum_k attn_k * (G[s_k] + R[r_k]) ), 4 cols per lane
        float4 acc = {0.f, 0.f, 0.f, 0.f};
        #pragma unroll
        for (int k = 0; k < TOPK; ++k) {
            float w = wk[k] * inv;
            float4 gv = ((const float4*)(G + (size_t)ts[k] * H))[l];
            float4 rv = ((const float4*)(R + (size_t)tr[k] * H))[l];
            acc.x += w * (gv.x + rv.x);
            acc.y += w * (gv.y + rv.y);
            acc.z += w * (gv.z + rv.z);
            acc.w += w * (gv.w + rv.w);
        }
        float4 o;
        o.x = tanhf(acc.x); o.y = tanhf(acc.y);
        o.z = tanhf(acc.z); o.w = tanhf(acc.w);
        ((float4*)(out + (size_t)i * H))[l] = o;
    }
}

// ---------------------------------------------------------------------------
extern "C" void kernel_launch(void* const* d_in, const int* in_sizes, int n_in,
                              void* d_out, int out_size, void* d_ws, size_t ws_size,
                              hipStream_t stream) {
    const float* ent = (const float*)d_in[0];   // 150000x128
    const float* rel = (const float*)d_in[1];   // 500x128
    const float* W   = (const float*)d_in[2];   // 128x128
    const float* Wr  = (const float*)d_in[3];   // 128x128
    const float* a   = (const float*)d_in[4];   // 384
    const float* nw  = (const float*)d_in[5];   // 128x128
    const int*   src = (const int*)d_in[6];     // 150000x32
    const int*   rid = (const int*)d_in[7];     // 150000x32
    float* out = (float*)d_out;                 // 150000x128

    // workspace layout (floats): total ~78.4 MB
    float* ws   = (float*)d_ws;
    float* M    = ws;                 // 16384
    float* M2   = M    + H * H;       // 16384
    float* v1   = M2   + H * H;       // 128
    float* v2   = v1   + H;           // 128
    float* u3   = v2   + H;           // 128
    float* R    = u3   + H;           // 64000
    float* srel = R    + N_REL * H;   // 500
    float* ssrc = srel + N_REL;       // 150000
    float* sdst = ssrc + N_ENT;       // 150000
    float* G    = sdst + N_ENT;       // 19200000

    precompute_small<<<H + 1, H, 0, stream>>>(W, Wr, nw, a, M, M2, v1, v2, u3);
    rel_transform  <<<N_REL, H, 0, stream>>>(rel, M2, u3, R, srel);
    node_scores    <<<512, 256, 0, stream>>>(ent, v1, v2, ssrc, sdst);
    ent_transform  <<<512, 256, 0, stream>>>(ent, M, G);
    gather_topk_out<<<2048, 256, 0, stream>>>(src, rid, ssrc, sdst, srel, G, R, out);
}

// Round 2
// 463.182 us; speedup vs baseline: 1.2087x; 1.2087x over previous
//
#include <hip/hip_runtime.h>
#include <hip/hip_bf16.h>
#include <math.h>

#define N_ENT 150000
#define N_REL 500
#define H     128
#define DEG   32
#define TOPK  10

typedef unsigned short ushort_t;
typedef unsigned int   uint_t;

__device__ inline ushort_t f2bf(float x) {
    __hip_bfloat16 h = __float2bfloat16(x);   // round-to-nearest-even
    return *reinterpret_cast<ushort_t*>(&h);
}
__device__ inline float bf2f(ushort_t u) {
    uint_t v = ((uint_t)u) << 16;
    return *reinterpret_cast<float*>(&v);
}

// ---------------------------------------------------------------------------
// Kernel A: tiny precomputes.
//   blocks 0..127 : row r of (W@nw) -> Mt TRANSPOSED (Mt[c][k]) ; M2 = W_r@nw
//   block  128    : v1 = W@a1, v2 = W@a2, u3 = W_r@a3
// ---------------------------------------------------------------------------
__global__ __launch_bounds__(128) void precompute_small(
    const float* __restrict__ W, const float* __restrict__ Wr,
    const float* __restrict__ nw, const float* __restrict__ a,
    float* __restrict__ Mt, float* __restrict__ M2,
    float* __restrict__ v1, float* __restrict__ v2, float* __restrict__ u3)
{
    int j = threadIdx.x;
    if (blockIdx.x < H) {
        int r = blockIdx.x;               // k-index of M
        float m = 0.f, m2 = 0.f;
        for (int t = 0; t < H; ++t) {
            float x = nw[t * H + j];      // coalesced across j
            m  += W [r * H + t] * x;      // uniform
            m2 += Wr[r * H + t] * x;
        }
        Mt[j * H + r] = m;                // transposed: col-major-of-M
        M2[r * H + j] = m2;
    } else {
        int h = j;
        float s1 = 0.f, s2 = 0.f, s3 = 0.f;
        for (int t = 0; t < H; ++t) {
            s1 += W [h * H + t] * a[t];
            s2 += W [h * H + t] * a[H + t];
            s3 += Wr[h * H + t] * a[2 * H + t];
        }
        v1[h] = s1; v2[h] = s2; u3[h] = s3;
    }
}

// ---------------------------------------------------------------------------
// Kernel B: R = rel_emb @ M2 (500x128, stored bf16), s_rel = rel_emb @ u3
// ---------------------------------------------------------------------------
__global__ __launch_bounds__(128) void rel_transform(
    const float* __restrict__ rel, const float* __restrict__ M2,
    const float* __restrict__ u3, ushort_t* __restrict__ Rb,
    float* __restrict__ srel)
{
    __shared__ float red[H];
    int r = blockIdx.x, j = threadIdx.x;
    float acc = 0.f;
    for (int h = 0; h < H; ++h)
        acc += rel[r * H + h] * M2[h * H + j];   // uniform * coalesced
    Rb[r * H + j] = f2bf(acc);
    red[j] = rel[r * H + j] * u3[j];
    __syncthreads();
    for (int s = 64; s > 0; s >>= 1) {
        if (j < s) red[j] += red[j + s];
        __syncthreads();
    }
    if (j == 0) srel[r] = red[0];
}

// ---------------------------------------------------------------------------
// Kernel C v2: G = ent_emb @ M (bf16 out) + fused s_src/s_dst.
// 128x128 tile per block. ent tile staged in LDS (64KB, 2 blocks/CU).
// Per-thread 8 rows x 8 cols register blocking: 256 FMA per 16 loads.
// Mt read from global (64KB total, shared by every block -> L1/L2 hot).
// k-chunk rotation by row-group avoids 4-way LDS bank conflicts.
// ---------------------------------------------------------------------------
__global__ __launch_bounds__(256, 2) void ent_transform2(
    const float* __restrict__ ent, const float* __restrict__ Mt,
    const float* __restrict__ v1, const float* __restrict__ v2,
    ushort_t* __restrict__ Gb, float* __restrict__ ssrc,
    float* __restrict__ sdst)
{
    __shared__ float Ae[128 * 128];       // 64KB
    const int t = threadIdx.x;
    const long base_row = (long)blockIdx.x * 128;

    // ---- stage ent tile (clamped for the 112-row tail tile) ----
    const long max_chunk = (long)N_ENT * (H / 4) - 1;   // last valid float4
    #pragma unroll
    for (int it = 0; it < 16; ++it) {
        long chunk = base_row * (H / 4) + it * 256 + t; // float4 index
        long g = chunk <= max_chunk ? chunk : max_chunk;
        float4 tmp = ((const float4*)ent)[g];
        ((float4*)Ae)[it * 256 + t] = tmp;
    }
    __syncthreads();

    // ---- fused node scores for this tile's rows (2 of 4 waves) ----
    if (t < 128) {
        long row = base_row + t;
        if (row < N_ENT) {
            float s1 = 0.f, s2 = 0.f;
            #pragma unroll
            for (int c = 0; c < 32; ++c) {
                int cc = (c + (t & 31)) & 31;   // stagger LDS banks
                float4 e  = *(const float4*)(&Ae[t * 128 + cc * 4]);
                float4 w1 = *(const float4*)(v1 + cc * 4);
                float4 w2 = *(const float4*)(v2 + cc * 4);
                s1 += e.x * w1.x + e.y * w1.y + e.z * w1.z + e.w * w1.w;
                s2 += e.x * w2.x + e.y * w2.y + e.z * w2.z + e.w * w2.w;
            }
            ssrc[row] = s1; sdst[row] = s2;
        }
    }

    // ---- main GEMM: 8 rows x 8 cols per thread ----
    const int cg = t & 15;          // column group: cols cg*8 .. cg*8+7
    const int rg = t >> 4;          // row group:    rows rg*8 .. rg*8+7
    const int r0 = rg * 8;
    const float* Bp = Mt + (size_t)cg * 8 * H;   // 8 columns of M, k-contig

    float acc[8][8];
    #pragma unroll
    for (int r = 0; r < 8; ++r)
        #pragma unroll
        for (int c = 0; c < 8; ++c) acc[r][c] = 0.f;

    for (int it = 0; it < 32; ++it) {
        int ci = (it + rg) & 31;    // rotate k-chunks across row-groups
        int k  = ci * 4;
        float4 b[8], a[8];
        #pragma unroll
        for (int c = 0; c < 8; ++c) b[c] = *(const float4*)(Bp + c * H + k);
        #pragma unroll
        for (int r = 0; r < 8; ++r) a[r] = *(const float4*)(&Ae[(r0 + r) * 128 + k]);
        #pragma unroll
        for (int r = 0; r < 8; ++r)
            #pragma unroll
            for (int c = 0; c < 8; ++c)
                acc[r][c] += a[r].x * b[c].x + a[r].y * b[c].y
                           + a[r].z * b[c].z + a[r].w * b[c].w;
    }

    // ---- store bf16 G (8 bf16 = 16B per row-slice, coalesced) ----
    #pragma unroll
    for (int r = 0; r < 8; ++r) {
        long row = base_row + r0 + r;
        if (row < N_ENT) {
            uint4 o;
            o.x = ((uint_t)f2bf(acc[r][1]) << 16) | f2bf(acc[r][0]);
            o.y = ((uint_t)f2bf(acc[r][3]) << 16) | f2bf(acc[r][2]);
            o.z = ((uint_t)f2bf(acc[r][5]) << 16) | f2bf(acc[r][4]);
            o.w = ((uint_t)f2bf(acc[r][7]) << 16) | f2bf(acc[r][6]);
            *(uint4*)(Gb + row * H + cg * 8) = o;
        }
    }
}

// ---------------------------------------------------------------------------
// Kernel D: fused score-gather + top-10 (max value, min index tie-break)
// + softmax + weighted bf16 G/R row gather + tanh. 32-lane half-wave / node.
// ---------------------------------------------------------------------------
__global__ __launch_bounds__(256) void gather_topk_out(
    const int* __restrict__ src, const int* __restrict__ rel_id,
    const float* __restrict__ ssrc, const float* __restrict__ sdst,
    const float* __restrict__ srel, const ushort_t* __restrict__ Gb,
    const ushort_t* __restrict__ Rb, float* __restrict__ out)
{
    int l   = threadIdx.x & 31;
    int hw  = (blockIdx.x * blockDim.x + threadIdx.x) >> 5;
    int nhw = (gridDim.x * blockDim.x) >> 5;
    for (int i = hw; i < N_ENT; i += nhw) {
        int sidx = src   [(size_t)i * DEG + l];
        int ridx = rel_id[(size_t)i * DEG + l];
        float x   = ssrc[sidx] + sdst[i] + srel[ridx];
        float val = x >= 0.f ? x : 0.2f * x;          // leaky_relu(0.2)

        // iterative argmax == jax.lax.top_k semantics
        float curv = val;
        float tvv[TOPK]; int ts[TOPK], tr[TOPK];
        #pragma unroll
        for (int k = 0; k < TOPK; ++k) {
            float v = curv; int id = l;
            #pragma unroll
            for (int off = 1; off < 32; off <<= 1) {
                float v2 = __shfl_xor(v, off, 32);
                int   i2 = __shfl_xor(id, off, 32);
                if (v2 > v || (v2 == v && i2 < id)) { v = v2; id = i2; }
            }
            tvv[k] = v;
            ts[k] = __shfl(sidx, id, 32);
            tr[k] = __shfl(ridx, id, 32);
            if (l == id) curv = -INFINITY;
        }

        // softmax over the 10 kept scores (tvv[0] is the max)
        float m = tvv[0], wsum = 0.f, wk[TOPK];
        #pragma unroll
        for (int k = 0; k < TOPK; ++k) { wk[k] = __expf(tvv[k] - m); wsum += wk[k]; }
        float inv = 1.f / wsum;

        // out[i] = tanh( sum_k attn_k * (G[s_k] + R[r_k]) ), 4 cols/lane
        float4 acc = {0.f, 0.f, 0.f, 0.f};
        #pragma unroll
        for (int k = 0; k < TOPK; ++k) {
            float w = wk[k] * inv;
            ushort4 gv = *(const ushort4*)(Gb + (size_t)ts[k] * H + l * 4);
            ushort4 rv = *(const ushort4*)(Rb + (size_t)tr[k] * H + l * 4);
            acc.x += w * (bf2f(gv.x) + bf2f(rv.x));
            acc.y += w * (bf2f(gv.y) + bf2f(rv.y));
            acc.z += w * (bf2f(gv.z) + bf2f(rv.z));
            acc.w += w * (bf2f(gv.w) + bf2f(rv.w));
        }
        float4 o;
        o.x = tanhf(acc.x); o.y = tanhf(acc.y);
        o.z = tanhf(acc.z); o.w = tanhf(acc.w);
        ((float4*)(out + (size_t)i * H))[l] = o;
    }
}

// ---------------------------------------------------------------------------
extern "C" void kernel_launch(void* const* d_in, const int* in_sizes, int n_in,
                              void* d_out, int out_size, void* d_ws, size_t ws_size,
                              hipStream_t stream) {
    const float* ent = (const float*)d_in[0];   // 150000x128
    const float* rel = (const float*)d_in[1];   // 500x128
    const float* W   = (const float*)d_in[2];   // 128x128
    const float* Wr  = (const float*)d_in[3];   // 128x128
    const float* a   = (const float*)d_in[4];   // 384
    const float* nw  = (const float*)d_in[5];   // 128x128
    const int*   src = (const int*)d_in[6];     // 150000x32
    const int*   rid = (const int*)d_in[7];     // 150000x32
    float* out = (float*)d_out;                 // 150000x128

    // workspace layout (float units; all offsets 16B-aligned)
    float* ws   = (float*)d_ws;
    float*    Mt   = ws;                     // 16384  (M transposed: [c][k])
    float*    M2   = Mt   + 16384;           // 16384
    float*    v1   = M2   + 16384;           // 128
    float*    v2   = v1   + 128;             // 128
    float*    u3   = v2   + 128;             // 128
    float*    srel = u3   + 128;             // 512 (padded)
    float*    ssrc = srel + 512;             // 150016
    float*    sdst = ssrc + 150016;          // 150016
    ushort_t* Rb   = (ushort_t*)(sdst + 150016);           // 64000 bf16
    ushort_t* Gb   = (ushort_t*)(sdst + 150016 + 32000);   // 19.2M bf16

    precompute_small<<<H + 1, H, 0, stream>>>(W, Wr, nw, a, Mt, M2, v1, v2, u3);
    rel_transform  <<<N_REL, H, 0, stream>>>(rel, M2, u3, Rb, srel);
    ent_transform2 <<<(N_ENT + 127) / 128, 256, 0, stream>>>(ent, Mt, v1, v2,
                                                             Gb, ssrc, sdst);
    gather_topk_out<<<2048, 256, 0, stream>>>(src, rid, ssrc, sdst, srel,
                                              Gb, Rb, out);
}

// Round 3
// 346.711 us; speedup vs baseline: 1.6148x; 1.3359x over previous
//
#include <hip/hip_runtime.h>
#include <hip/hip_bf16.h>
#include <math.h>

#define N_ENT 150000
#define N_REL 500
#define H     128
#define DEG   32
#define TOPK  10

typedef unsigned short ushort_t;
typedef unsigned int   uint_t;
typedef __attribute__((ext_vector_type(8))) short short8;
typedef __attribute__((ext_vector_type(4))) float f32x4;

__device__ inline ushort_t f2bf(float x) {
    __hip_bfloat16 h = __float2bfloat16(x);   // RNE
    return *reinterpret_cast<ushort_t*>(&h);
}
__device__ inline float bf2f(ushort_t u) {
    uint_t v = ((uint_t)u) << 16;
    return *reinterpret_cast<float*>(&v);
}
__device__ inline float dot4(float4 a, float4 b) {
    return a.x * b.x + a.y * b.y + a.z * b.z + a.w * b.w;
}
__device__ inline float fast_tanh(float x) {
    float e = __expf(2.f * x);                 // v_exp_f32
    return 1.f - 2.f * __builtin_amdgcn_rcpf(e + 1.f);
}

// ---------------------------------------------------------------------------
// Kernel A: tiny precomputes.
//   blocks 0..127 : row k of M = W@nw (row-major) and M2 = W_r@nw
//   block  128    : v1 = W@a1, v2 = W@a2, u3 = W_r@a3
// ---------------------------------------------------------------------------
__global__ __launch_bounds__(128) void precompute_small(
    const float* __restrict__ W, const float* __restrict__ Wr,
    const float* __restrict__ nw, const float* __restrict__ a,
    float* __restrict__ M, float* __restrict__ M2,
    float* __restrict__ v1, float* __restrict__ v2, float* __restrict__ u3)
{
    int j = threadIdx.x;
    if (blockIdx.x < H) {
        int r = blockIdx.x;
        float m = 0.f, m2 = 0.f;
        for (int t = 0; t < H; ++t) {
            float x = nw[t * H + j];
            m  += W [r * H + t] * x;
            m2 += Wr[r * H + t] * x;
        }
        M [r * H + j] = m;
        M2[r * H + j] = m2;
    } else {
        int h = j;
        float s1 = 0.f, s2 = 0.f, s3 = 0.f;
        for (int t = 0; t < H; ++t) {
            s1 += W [h * H + t] * a[t];
            s2 += W [h * H + t] * a[H + t];
            s3 += Wr[h * H + t] * a[2 * H + t];
        }
        v1[h] = s1; v2[h] = s2; u3[h] = s3;
    }
}

// ---------------------------------------------------------------------------
// Kernel A2: build B fragments of M in MFMA lane layout, bf16 hi/lo.
// B[k][n]: n = lane&15, k = ktile*32 + (lane>>4)*8 + j.
// Layout: Bfrag[(c*4+t)*64 + lane][j]  (8 bf16 = 16B per lane, b128-loadable)
// ---------------------------------------------------------------------------
__global__ __launch_bounds__(64) void bfrag_build(
    const float* __restrict__ M, ushort_t* __restrict__ Bhi,
    ushort_t* __restrict__ Blo)
{
    int b = blockIdx.x;           // 0..31 = c*4 + t
    int c = b >> 2, tt = b & 3;
    int l = threadIdx.x;
    int n  = c * 16 + (l & 15);
    int k0 = tt * 32 + (l >> 4) * 8;
    #pragma unroll
    for (int j = 0; j < 8; ++j) {
        float x = M[(k0 + j) * H + n];
        ushort_t h = f2bf(x);
        Bhi[(size_t)(b * 64 + l) * 8 + j] = h;
        Blo[(size_t)(b * 64 + l) * 8 + j] = f2bf(x - bf2f(h));
    }
}

// ---------------------------------------------------------------------------
// Kernel B: R = rel_emb @ M2 (500x128, bf16), s_rel = rel_emb @ u3
// ---------------------------------------------------------------------------
__global__ __launch_bounds__(128) void rel_transform(
    const float* __restrict__ rel, const float* __restrict__ M2,
    const float* __restrict__ u3, ushort_t* __restrict__ Rb,
    float* __restrict__ srel)
{
    __shared__ float red[H];
    int r = blockIdx.x, j = threadIdx.x;
    float acc = 0.f;
    for (int h = 0; h < H; ++h)
        acc += rel[r * H + h] * M2[h * H + j];
    Rb[r * H + j] = f2bf(acc);
    red[j] = rel[r * H + j] * u3[j];
    __syncthreads();
    for (int s = 64; s > 0; s >>= 1) {
        if (j < s) red[j] += red[j + s];
        __syncthreads();
    }
    if (j == 0) srel[r] = red[0];
}

// ---------------------------------------------------------------------------
// Kernel C v3: G = ent @ M via bf16 hi/lo MFMA (fp32-grade accuracy) + fused
// exact-f32 node scores. 32 rows/wave, 128 rows/block, no LDS, no barriers.
// A fragments loaded straight from global in MFMA lane layout; B fragments
// (64KB total) read from the prebuilt global arrays -> L1/L2 hot everywhere.
// ---------------------------------------------------------------------------
__global__ __launch_bounds__(256) void ent_transform3(
    const float* __restrict__ ent, const ushort_t* __restrict__ Bhi,
    const ushort_t* __restrict__ Blo, const float* __restrict__ v1,
    const float* __restrict__ v2, ushort_t* __restrict__ Gb,
    float* __restrict__ ssrc, float* __restrict__ sdst)
{
    const int t    = threadIdx.x;
    const int w    = t >> 6;       // wave 0..3
    const int l    = t & 63;
    const int m    = l & 15;
    const int quad = l >> 4;
    const long blockRow = (long)blockIdx.x * 128;
    const long waveRow  = blockRow + (long)w * 32;

    // per-lane slices of v1/v2 matching A-fragment k indices
    float4 v1a[4], v1b[4], v2a[4], v2b[4];
    #pragma unroll
    for (int tt = 0; tt < 4; ++tt) {
        const float* p1 = v1 + tt * 32 + quad * 8;
        const float* p2 = v2 + tt * 32 + quad * 8;
        v1a[tt] = *(const float4*)p1; v1b[tt] = *(const float4*)(p1 + 4);
        v2a[tt] = *(const float4*)p2; v2b[tt] = *(const float4*)(p2 + 4);
    }

    // ---- load A fragments (2 row-sets x 4 k-tiles), hi/lo split + scores --
    short8 Ahi[2][4], Alo[2][4];
    float p1s[2] = {0.f, 0.f}, p2s[2] = {0.f, 0.f};
    #pragma unroll
    for (int s = 0; s < 2; ++s) {
        long row = waveRow + s * 16 + m;
        long rc  = row < N_ENT ? row : (N_ENT - 1);
        const float* rp = ent + rc * H;
        #pragma unroll
        for (int tt = 0; tt < 4; ++tt) {
            float4 e0 = *(const float4*)(rp + tt * 32 + quad * 8);
            float4 e1 = *(const float4*)(rp + tt * 32 + quad * 8 + 4);
            p1s[s] += dot4(e0, v1a[tt]) + dot4(e1, v1b[tt]);
            p2s[s] += dot4(e0, v2a[tt]) + dot4(e1, v2b[tt]);
            float x[8] = {e0.x, e0.y, e0.z, e0.w, e1.x, e1.y, e1.z, e1.w};
            #pragma unroll
            for (int j = 0; j < 8; ++j) {
                ushort_t h = f2bf(x[j]);
                Ahi[s][tt][j] = (short)h;
                Alo[s][tt][j] = (short)f2bf(x[j] - bf2f(h));
            }
        }
    }
    // quad-butterfly: all 4 quads get the full row dot product
    #pragma unroll
    for (int s = 0; s < 2; ++s) {
        p1s[s] += __shfl_xor(p1s[s], 16); p1s[s] += __shfl_xor(p1s[s], 32);
        p2s[s] += __shfl_xor(p2s[s], 16); p2s[s] += __shfl_xor(p2s[s], 32);
    }
    if (quad == 0) {
        #pragma unroll
        for (int s = 0; s < 2; ++s) {
            long row = waveRow + s * 16 + m;
            if (row < N_ENT) { ssrc[row] = p1s[s]; sdst[row] = p2s[s]; }
        }
    }

    // ---- MFMA main loop over 8 column tiles ----
    for (int c = 0; c < 8; ++c) {
        short8 bh[4], bl[4];
        #pragma unroll
        for (int tt = 0; tt < 4; ++tt) {
            size_t off = (size_t)((c * 4 + tt) * 64 + l) * 8;
            bh[tt] = *(const short8*)(Bhi + off);
            bl[tt] = *(const short8*)(Blo + off);
        }
        f32x4 acc0 = {0.f, 0.f, 0.f, 0.f}, acc1 = {0.f, 0.f, 0.f, 0.f};
        #pragma unroll
        for (int tt = 0; tt < 4; ++tt) {
            acc0 = __builtin_amdgcn_mfma_f32_16x16x32_bf16(Ahi[0][tt], bh[tt], acc0, 0, 0, 0);
            acc0 = __builtin_amdgcn_mfma_f32_16x16x32_bf16(Alo[0][tt], bh[tt], acc0, 0, 0, 0);
            acc0 = __builtin_amdgcn_mfma_f32_16x16x32_bf16(Ahi[0][tt], bl[tt], acc0, 0, 0, 0);
            acc1 = __builtin_amdgcn_mfma_f32_16x16x32_bf16(Ahi[1][tt], bh[tt], acc1, 0, 0, 0);
            acc1 = __builtin_amdgcn_mfma_f32_16x16x32_bf16(Alo[1][tt], bh[tt], acc1, 0, 0, 0);
            acc1 = __builtin_amdgcn_mfma_f32_16x16x32_bf16(Ahi[1][tt], bl[tt], acc1, 0, 0, 0);
        }
        // store: D row = quad*4+reg, col = m  (bf16, 2B/lane per store)
        #pragma unroll
        for (int s = 0; s < 2; ++s) {
            f32x4 a = s ? acc1 : acc0;
            #pragma unroll
            for (int r = 0; r < 4; ++r) {
                long row = waveRow + s * 16 + quad * 4 + r;
                if (row < N_ENT)
                    Gb[row * H + c * 16 + m] = f2bf(a[r]);
            }
        }
    }
}

// ---------------------------------------------------------------------------
// Kernel D: fused score-gather + top-10 (max value, min index tie-break)
// + softmax + weighted bf16 G/R row gather + fast tanh. Half-wave per node.
// ---------------------------------------------------------------------------
__global__ __launch_bounds__(256) void gather_topk_out(
    const int* __restrict__ src, const int* __restrict__ rel_id,
    const float* __restrict__ ssrc, const float* __restrict__ sdst,
    const float* __restrict__ srel, const ushort_t* __restrict__ Gb,
    const ushort_t* __restrict__ Rb, float* __restrict__ out)
{
    int l   = threadIdx.x & 31;
    int hw  = (blockIdx.x * blockDim.x + threadIdx.x) >> 5;
    int nhw = (gridDim.x * blockDim.x) >> 5;
    for (int i = hw; i < N_ENT; i += nhw) {
        int sidx = src   [(size_t)i * DEG + l];
        int ridx = rel_id[(size_t)i * DEG + l];
        float x   = ssrc[sidx] + sdst[i] + srel[ridx];
        float val = x >= 0.f ? x : 0.2f * x;          // leaky_relu(0.2)

        // iterative argmax == jax.lax.top_k semantics
        float curv = val;
        float tvv[TOPK]; int ts[TOPK], tr[TOPK];
        #pragma unroll
        for (int k = 0; k < TOPK; ++k) {
            float v = curv; int id = l;
            #pragma unroll
            for (int off = 1; off < 32; off <<= 1) {
                float v2 = __shfl_xor(v, off, 32);
                int   i2 = __shfl_xor(id, off, 32);
                if (v2 > v || (v2 == v && i2 < id)) { v = v2; id = i2; }
            }
            tvv[k] = v;
            ts[k] = __shfl(sidx, id, 32);
            tr[k] = __shfl(ridx, id, 32);
            if (l == id) curv = -INFINITY;
        }

        // softmax over the 10 kept scores (tvv[0] is the max)
        float mx = tvv[0], wsum = 0.f, wk[TOPK];
        #pragma unroll
        for (int k = 0; k < TOPK; ++k) { wk[k] = __expf(tvv[k] - mx); wsum += wk[k]; }
        float inv = __builtin_amdgcn_rcpf(wsum);

        // out[i] = tanh( sum_k attn_k * (G[s_k] + R[r_k]) ), 4 cols/lane
        float4 acc = {0.f, 0.f, 0.f, 0.f};
        #pragma unroll
        for (int k = 0; k < TOPK; ++k) {
            float w = wk[k] * inv;
            ushort4 gv = *(const ushort4*)(Gb + (size_t)ts[k] * H + l * 4);
            ushort4 rv = *(const ushort4*)(Rb + (size_t)tr[k] * H + l * 4);
            acc.x += w * (bf2f(gv.x) + bf2f(rv.x));
            acc.y += w * (bf2f(gv.y) + bf2f(rv.y));
            acc.z += w * (bf2f(gv.z) + bf2f(rv.z));
            acc.w += w * (bf2f(gv.w) + bf2f(rv.w));
        }
        float4 o;
        o.x = fast_tanh(acc.x); o.y = fast_tanh(acc.y);
        o.z = fast_tanh(acc.z); o.w = fast_tanh(acc.w);
        ((float4*)(out + (size_t)i * H))[l] = o;
    }
}

// ---------------------------------------------------------------------------
extern "C" void kernel_launch(void* const* d_in, const int* in_sizes, int n_in,
                              void* d_out, int out_size, void* d_ws, size_t ws_size,
                              hipStream_t stream) {
    const float* ent = (const float*)d_in[0];   // 150000x128
    const float* rel = (const float*)d_in[1];   // 500x128
    const float* W   = (const float*)d_in[2];   // 128x128
    const float* Wr  = (const float*)d_in[3];   // 128x128
    const float* a   = (const float*)d_in[4];   // 384
    const float* nw  = (const float*)d_in[5];   // 128x128
    const int*   src = (const int*)d_in[6];     // 150000x32
    const int*   rid = (const int*)d_in[7];     // 150000x32
    float* out = (float*)d_out;                 // 150000x128

    // workspace layout (float units; all offsets 16B-aligned)
    float* ws = (float*)d_ws;
    float*    M    = ws;                     // 16384
    float*    M2   = M    + 16384;           // 16384
    float*    v1   = M2   + 16384;           // 128
    float*    v2   = v1   + 128;             // 128
    float*    u3   = v2   + 128;             // 128
    float*    srel = u3   + 128;             // 512 (padded)
    float*    ssrc = srel + 512;             // 150016
    float*    sdst = ssrc + 150016;          // 150016
    ushort_t* Bhi  = (ushort_t*)(sdst + 150016);            // 16384 bf16
    ushort_t* Blo  = Bhi + 16384;                           // 16384 bf16
    ushort_t* Rb   = Blo + 16384;                           // 64000 bf16
    ushort_t* Gb   = Rb  + 64000;                           // 19.2M bf16

    precompute_small<<<H + 1, H, 0, stream>>>(W, Wr, nw, a, M, M2, v1, v2, u3);
    bfrag_build    <<<32, 64, 0, stream>>>(M, Bhi, Blo);
    rel_transform  <<<N_REL, H, 0, stream>>>(rel, M2, u3, Rb, srel);
    ent_transform3 <<<(N_ENT + 127) / 128, 256, 0, stream>>>(ent, Bhi, Blo,
                                                             v1, v2, Gb, ssrc, sdst);
    gather_topk_out<<<2048, 256, 0, stream>>>(src, rid, ssrc, sdst, srel,
                                              Gb, Rb, out);
}

// Round 4
// 329.359 us; speedup vs baseline: 1.6998x; 1.0527x over previous
//
#include <hip/hip_runtime.h>
#include <hip/hip_bf16.h>
#include <math.h>

#define N_ENT 150000
#define N_REL 500
#define H     128
#define DEG   32
#define TOPK  10

typedef unsigned short ushort_t;
typedef unsigned int   uint_t;
typedef __attribute__((ext_vector_type(8))) short short8;
typedef __attribute__((ext_vector_type(4))) float f32x4;

__device__ inline ushort_t f2bf(float x) {
    __hip_bfloat16 h = __float2bfloat16(x);   // RNE
    return *reinterpret_cast<ushort_t*>(&h);
}
__device__ inline float bf2f(ushort_t u) {
    uint_t v = ((uint_t)u) << 16;
    return *reinterpret_cast<float*>(&v);
}
__device__ inline float dot4(float4 a, float4 b) {
    return a.x * b.x + a.y * b.y + a.z * b.z + a.w * b.w;
}
__device__ inline float fast_tanh(float x) {
    float e = __expf(2.f * x);                 // v_exp_f32
    return 1.f - 2.f * __builtin_amdgcn_rcpf(e + 1.f);
}

// ---------------------------------------------------------------------------
// Kernel A: tiny precomputes.
//   blocks 0..127 : row k of M = W@nw (row-major) and M2 = W_r@nw
//   block  128    : v1 = W@a1, v2 = W@a2, u3 = W_r@a3
// ---------------------------------------------------------------------------
__global__ __launch_bounds__(128) void precompute_small(
    const float* __restrict__ W, const float* __restrict__ Wr,
    const float* __restrict__ nw, const float* __restrict__ a,
    float* __restrict__ M, float* __restrict__ M2,
    float* __restrict__ v1, float* __restrict__ v2, float* __restrict__ u3)
{
    int j = threadIdx.x;
    if (blockIdx.x < H) {
        int r = blockIdx.x;
        float m = 0.f, m2 = 0.f;
        for (int t = 0; t < H; ++t) {
            float x = nw[t * H + j];
            m  += W [r * H + t] * x;
            m2 += Wr[r * H + t] * x;
        }
        M [r * H + j] = m;
        M2[r * H + j] = m2;
    } else {
        int h = j;
        float s1 = 0.f, s2 = 0.f, s3 = 0.f;
        for (int t = 0; t < H; ++t) {
            s1 += W [h * H + t] * a[t];
            s2 += W [h * H + t] * a[H + t];
            s3 += Wr[h * H + t] * a[2 * H + t];
        }
        v1[h] = s1; v2[h] = s2; u3[h] = s3;
    }
}

// ---------------------------------------------------------------------------
// Kernel A2: build B fragments of M in MFMA lane layout, bf16 hi/lo.
// ---------------------------------------------------------------------------
__global__ __launch_bounds__(64) void bfrag_build(
    const float* __restrict__ M, ushort_t* __restrict__ Bhi,
    ushort_t* __restrict__ Blo)
{
    int b = blockIdx.x;           // 0..31 = c*4 + t
    int c = b >> 2, tt = b & 3;
    int l = threadIdx.x;
    int n  = c * 16 + (l & 15);
    int k0 = tt * 32 + (l >> 4) * 8;
    #pragma unroll
    for (int j = 0; j < 8; ++j) {
        float x = M[(k0 + j) * H + n];
        ushort_t h = f2bf(x);
        Bhi[(size_t)(b * 64 + l) * 8 + j] = h;
        Blo[(size_t)(b * 64 + l) * 8 + j] = f2bf(x - bf2f(h));
    }
}

// ---------------------------------------------------------------------------
// Kernel B: R = rel_emb @ M2 (500x128, bf16), s_rel = rel_emb @ u3
// ---------------------------------------------------------------------------
__global__ __launch_bounds__(128) void rel_transform(
    const float* __restrict__ rel, const float* __restrict__ M2,
    const float* __restrict__ u3, ushort_t* __restrict__ Rb,
    float* __restrict__ srel)
{
    __shared__ float red[H];
    int r = blockIdx.x, j = threadIdx.x;
    float acc = 0.f;
    for (int h = 0; h < H; ++h)
        acc += rel[r * H + h] * M2[h * H + j];
    Rb[r * H + j] = f2bf(acc);
    red[j] = rel[r * H + j] * u3[j];
    __syncthreads();
    for (int s = 64; s > 0; s >>= 1) {
        if (j < s) red[j] += red[j + s];
        __syncthreads();
    }
    if (j == 0) srel[r] = red[0];
}

// ---------------------------------------------------------------------------
// Kernel C v3: G = ent @ M via bf16 hi/lo MFMA + fused exact-f32 node scores.
// ---------------------------------------------------------------------------
__global__ __launch_bounds__(256) void ent_transform3(
    const float* __restrict__ ent, const ushort_t* __restrict__ Bhi,
    const ushort_t* __restrict__ Blo, const float* __restrict__ v1,
    const float* __restrict__ v2, ushort_t* __restrict__ Gb,
    float* __restrict__ ssrc, float* __restrict__ sdst)
{
    const int t    = threadIdx.x;
    const int w    = t >> 6;       // wave 0..3
    const int l    = t & 63;
    const int m    = l & 15;
    const int quad = l >> 4;
    const long blockRow = (long)blockIdx.x * 128;
    const long waveRow  = blockRow + (long)w * 32;

    float4 v1a[4], v1b[4], v2a[4], v2b[4];
    #pragma unroll
    for (int tt = 0; tt < 4; ++tt) {
        const float* p1 = v1 + tt * 32 + quad * 8;
        const float* p2 = v2 + tt * 32 + quad * 8;
        v1a[tt] = *(const float4*)p1; v1b[tt] = *(const float4*)(p1 + 4);
        v2a[tt] = *(const float4*)p2; v2b[tt] = *(const float4*)(p2 + 4);
    }

    short8 Ahi[2][4], Alo[2][4];
    float p1s[2] = {0.f, 0.f}, p2s[2] = {0.f, 0.f};
    #pragma unroll
    for (int s = 0; s < 2; ++s) {
        long row = waveRow + s * 16 + m;
        long rc  = row < N_ENT ? row : (N_ENT - 1);
        const float* rp = ent + rc * H;
        #pragma unroll
        for (int tt = 0; tt < 4; ++tt) {
            float4 e0 = *(const float4*)(rp + tt * 32 + quad * 8);
            float4 e1 = *(const float4*)(rp + tt * 32 + quad * 8 + 4);
            p1s[s] += dot4(e0, v1a[tt]) + dot4(e1, v1b[tt]);
            p2s[s] += dot4(e0, v2a[tt]) + dot4(e1, v2b[tt]);
            float x[8] = {e0.x, e0.y, e0.z, e0.w, e1.x, e1.y, e1.z, e1.w};
            #pragma unroll
            for (int j = 0; j < 8; ++j) {
                ushort_t h = f2bf(x[j]);
                Ahi[s][tt][j] = (short)h;
                Alo[s][tt][j] = (short)f2bf(x[j] - bf2f(h));
            }
        }
    }
    #pragma unroll
    for (int s = 0; s < 2; ++s) {
        p1s[s] += __shfl_xor(p1s[s], 16); p1s[s] += __shfl_xor(p1s[s], 32);
        p2s[s] += __shfl_xor(p2s[s], 16); p2s[s] += __shfl_xor(p2s[s], 32);
    }
    if (quad == 0) {
        #pragma unroll
        for (int s = 0; s < 2; ++s) {
            long row = waveRow + s * 16 + m;
            if (row < N_ENT) { ssrc[row] = p1s[s]; sdst[row] = p2s[s]; }
        }
    }

    for (int c = 0; c < 8; ++c) {
        short8 bh[4], bl[4];
        #pragma unroll
        for (int tt = 0; tt < 4; ++tt) {
            size_t off = (size_t)((c * 4 + tt) * 64 + l) * 8;
            bh[tt] = *(const short8*)(Bhi + off);
            bl[tt] = *(const short8*)(Blo + off);
        }
        f32x4 acc0 = {0.f, 0.f, 0.f, 0.f}, acc1 = {0.f, 0.f, 0.f, 0.f};
        #pragma unroll
        for (int tt = 0; tt < 4; ++tt) {
            acc0 = __builtin_amdgcn_mfma_f32_16x16x32_bf16(Ahi[0][tt], bh[tt], acc0, 0, 0, 0);
            acc0 = __builtin_amdgcn_mfma_f32_16x16x32_bf16(Alo[0][tt], bh[tt], acc0, 0, 0, 0);
            acc0 = __builtin_amdgcn_mfma_f32_16x16x32_bf16(Ahi[0][tt], bl[tt], acc0, 0, 0, 0);
            acc1 = __builtin_amdgcn_mfma_f32_16x16x32_bf16(Ahi[1][tt], bh[tt], acc1, 0, 0, 0);
            acc1 = __builtin_amdgcn_mfma_f32_16x16x32_bf16(Alo[1][tt], bh[tt], acc1, 0, 0, 0);
            acc1 = __builtin_amdgcn_mfma_f32_16x16x32_bf16(Ahi[1][tt], bl[tt], acc1, 0, 0, 0);
        }
        #pragma unroll
        for (int s = 0; s < 2; ++s) {
            f32x4 a = s ? acc1 : acc0;
            #pragma unroll
            for (int r = 0; r < 4; ++r) {
                long row = waveRow + s * 16 + quad * 4 + r;
                if (row < N_ENT)
                    Gb[row * H + c * 16 + m] = f2bf(a[r]);
            }
        }
    }
}

// ---------------------------------------------------------------------------
// Kernel D v2: rank-based top-10 selection (order-invariant downstream math).
// rank_i = #{j : v_j > v_i or (v_j==v_i && j<i)}  == jax top_k set semantics.
// 31 xor-shuffles for rank (partner idx = l^xm is free), butterfly max+sum,
// packed (sidx|ridx<<18) broadcast = 2 bpermutes/k, batched G/R loads.
// ---------------------------------------------------------------------------
__global__ __launch_bounds__(256) void gather_topk_out(
    const int* __restrict__ src, const int* __restrict__ rel_id,
    const float* __restrict__ ssrc, const float* __restrict__ sdst,
    const float* __restrict__ srel, const ushort_t* __restrict__ Gb,
    const ushort_t* __restrict__ Rb, float* __restrict__ out)
{
    const int l         = threadIdx.x & 31;
    const int halfShift = threadIdx.x & 32;    // 0 or 32
    int hw  = (blockIdx.x * blockDim.x + threadIdx.x) >> 5;
    int nhw = (gridDim.x * blockDim.x) >> 5;

    for (int i = hw; i < N_ENT; i += nhw) {
        int sidx = src   [(size_t)i * DEG + l];
        int ridx = rel_id[(size_t)i * DEG + l];
        float x   = ssrc[sidx] + sdst[i] + srel[ridx];
        float val = x >= 0.f ? x : 0.2f * x;          // leaky_relu(0.2)

        // rank among the 32 edges (desc value, asc index)
        int rank = 0;
        #pragma unroll
        for (int xm = 1; xm < 32; ++xm) {
            float v2 = __shfl_xor(val, xm, 32);
            bool ahead = (v2 > val) || (v2 == val && (l ^ xm) < l);
            rank += ahead ? 1 : 0;
        }
        bool sel = rank < TOPK;

        // butterfly max (global max is in the top-10 -> exact softmax shift)
        float mx = val;
        #pragma unroll
        for (int off = 1; off < 32; off <<= 1)
            mx = fmaxf(mx, __shfl_xor(mx, off, 32));

        float e  = sel ? __expf(val - mx) : 0.f;
        float ws = e;
        #pragma unroll
        for (int off = 1; off < 32; off <<= 1)
            ws += __shfl_xor(ws, off, 32);
        float w = e * __builtin_amdgcn_rcpf(ws);

        // selected-lane mask for this half-wave
        unsigned long long ball = __ballot(sel);
        uint_t mask = (uint_t)(ball >> halfShift);

        // broadcast 10 tuples: packed idx + weight (2 bpermutes per k)
        uint_t packed = (uint_t)sidx | ((uint_t)ridx << 18);
        uint_t pk[TOPK]; float wk[TOPK];
        #pragma unroll
        for (int k = 0; k < TOPK; ++k) {
            int lk = (int)__builtin_ctz(mask); mask &= mask - 1;
            pk[k] = (uint_t)__shfl((int)packed, lk, 32);
            wk[k] = __shfl(w, lk, 32);
        }

        // batch all 20 row-gathers into registers, then FMA
        ushort4 gv[TOPK], rv[TOPK];
        #pragma unroll
        for (int k = 0; k < TOPK; ++k) {
            size_t s_k = pk[k] & 0x3FFFF;
            size_t r_k = pk[k] >> 18;
            gv[k] = *(const ushort4*)(Gb + s_k * H + l * 4);
            rv[k] = *(const ushort4*)(Rb + r_k * H + l * 4);
        }
        float4 acc = {0.f, 0.f, 0.f, 0.f};
        #pragma unroll
        for (int k = 0; k < TOPK; ++k) {
            float wv = wk[k];
            acc.x += wv * (bf2f(gv[k].x) + bf2f(rv[k].x));
            acc.y += wv * (bf2f(gv[k].y) + bf2f(rv[k].y));
            acc.z += wv * (bf2f(gv[k].z) + bf2f(rv[k].z));
            acc.w += wv * (bf2f(gv[k].w) + bf2f(rv[k].w));
        }
        float4 o;
        o.x = fast_tanh(acc.x); o.y = fast_tanh(acc.y);
        o.z = fast_tanh(acc.z); o.w = fast_tanh(acc.w);
        ((float4*)(out + (size_t)i * H))[l] = o;
    }
}

// ---------------------------------------------------------------------------
extern "C" void kernel_launch(void* const* d_in, const int* in_sizes, int n_in,
                              void* d_out, int out_size, void* d_ws, size_t ws_size,
                              hipStream_t stream) {
    const float* ent = (const float*)d_in[0];   // 150000x128
    const float* rel = (const float*)d_in[1];   // 500x128
    const float* W   = (const float*)d_in[2];   // 128x128
    const float* Wr  = (const float*)d_in[3];   // 128x128
    const float* a   = (const float*)d_in[4];   // 384
    const float* nw  = (const float*)d_in[5];   // 128x128
    const int*   src = (const int*)d_in[6];     // 150000x32
    const int*   rid = (const int*)d_in[7];     // 150000x32
    float* out = (float*)d_out;                 // 150000x128

    float* ws = (float*)d_ws;
    float*    M    = ws;                     // 16384
    float*    M2   = M    + 16384;           // 16384
    float*    v1   = M2   + 16384;           // 128
    float*    v2   = v1   + 128;             // 128
    float*    u3   = v2   + 128;             // 128
    float*    srel = u3   + 128;             // 512 (padded)
    float*    ssrc = srel + 512;             // 150016
    float*    sdst = ssrc + 150016;          // 150016
    ushort_t* Bhi  = (ushort_t*)(sdst + 150016);            // 16384 bf16
    ushort_t* Blo  = Bhi + 16384;                           // 16384 bf16
    ushort_t* Rb   = Blo + 16384;                           // 64000 bf16
    ushort_t* Gb   = Rb  + 64000;                           // 19.2M bf16

    precompute_small<<<H + 1, H, 0, stream>>>(W, Wr, nw, a, M, M2, v1, v2, u3);
    bfrag_build    <<<32, 64, 0, stream>>>(M, Bhi, Blo);
    rel_transform  <<<N_REL, H, 0, stream>>>(rel, M2, u3, Rb, srel);
    ent_transform3 <<<(N_ENT + 127) / 128, 256, 0, stream>>>(ent, Bhi, Blo,
                                                             v1, v2, Gb, ssrc, sdst);
    gather_topk_out<<<2048, 256, 0, stream>>>(src, rid, ssrc, sdst, srel,
                                              Gb, Rb, out);
}